// Round 11
// baseline (663.112 us; speedup 1.0000x reference)
//
#include <hip/hip_runtime.h>

#define N_NODES 100000
#define N_EDGES 20000
#define NNZV    1600000
#define NSEG    (N_EDGES + N_NODES)
#define FIN     128
#define HSLICES 64
#define SLICE   (NNZV / HSLICES)    // 25000
#define NR_E    4                   // edge ranges of 5000
#define NR_N    16                  // node ranges of 6250
#define NRANGES (NR_E + NR_N)       // 20

// ---- bf16 helpers (RTNE pack, cheap unpack) ----
__device__ __forceinline__ unsigned short f2bf(float f) {
  unsigned u = __float_as_uint(f);
  unsigned r = u + 0x7fffu + ((u >> 16) & 1u);
  return (unsigned short)(r >> 16);
}
__device__ __forceinline__ unsigned pack2(float lo, float hi) {
  return (unsigned)f2bf(lo) | ((unsigned)f2bf(hi) << 16);
}
__device__ __forceinline__ float bf_lo(unsigned w) { return __uint_as_float(w << 16); }
__device__ __forceinline__ float bf_hi(unsigned w) { return __uint_as_float(w & 0xffff0000u); }

// range decomposition: r<NR_E -> edge bins [r*5000,(r+1)*5000), else node bins
__device__ __forceinline__ void range_info(int r, const int* nidx, const int* eidx,
                                           const int*& keys, const int*& vals,
                                           int& base, int& size, int& gbin_off) {
  if (r < NR_E) { keys = eidx; vals = nidx; base = r * 5000; size = 5000; gbin_off = 0; }
  else { keys = nidx; vals = eidx; base = (r - NR_E) * 6250; size = 6250; gbin_off = N_EDGES; }
}

// ---------------- histogram count: part[s][bin], LDS, no device atomics ----------------

__global__ __launch_bounds__(256) void k_hist(const int* __restrict__ nidx,
                                              const int* __restrict__ eidx,
                                              int* __restrict__ part) {
  __shared__ int hist[6250];
  int r = blockIdx.x % NRANGES, s = blockIdx.x / NRANGES;
  const int *keys, *vals; int base, size, gbin_off;
  range_info(r, nidx, eidx, keys, vals, base, size, gbin_off);
  for (int i = threadIdx.x; i < size; i += 256) hist[i] = 0;
  __syncthreads();
  int lo = s * SLICE, hi = lo + SLICE;
  for (int i = lo + threadIdx.x; i < hi; i += 256) {
    int k = keys[i];
    unsigned d = (unsigned)(k - base);
    if (d < (unsigned)size) atomicAdd(&hist[d], 1);
  }
  __syncthreads();
  int* dst = part + (size_t)s * NSEG + gbin_off + base;
  for (int i = threadIdx.x; i < size; i += 256) dst[i] = hist[i];
}

__global__ void k_hreduce(const int* __restrict__ part, int* __restrict__ cnt) {
  int b = blockIdx.x * 256 + threadIdx.x;
  if (b >= NSEG) return;
  int sum = 0;
  for (int s = 0; s < HSLICES; ++s) sum += part[(size_t)s * NSEG + b];
  cnt[b] = sum;
}

// ---------------- scans ----------------

__global__ void k_scan1(const int* __restrict__ cnt, int* __restrict__ incl,
                        int* __restrict__ bsum) {
  __shared__ int s[1024];
  int gid = blockIdx.x * 1024 + threadIdx.x;
  int v = (gid < NSEG) ? cnt[gid] : 0;
  s[threadIdx.x] = v;
  __syncthreads();
  for (int d = 1; d < 1024; d <<= 1) {
    int t = (threadIdx.x >= d) ? s[threadIdx.x - d] : 0;
    __syncthreads();
    s[threadIdx.x] += t;
    __syncthreads();
  }
  if (gid < NSEG) incl[gid] = s[threadIdx.x];
  if (threadIdx.x == 1023) bsum[blockIdx.x] = s[1023];
}

__global__ void k_scan2(int* __restrict__ bsum, int nb) {
  __shared__ int s[128];
  int v = (threadIdx.x < nb) ? bsum[threadIdx.x] : 0;
  s[threadIdx.x] = v;
  __syncthreads();
  for (int d = 1; d < 128; d <<= 1) {
    int t = (threadIdx.x >= (unsigned)d) ? s[threadIdx.x - d] : 0;
    __syncthreads();
    s[threadIdx.x] += t;
    __syncthreads();
  }
  if (threadIdx.x < nb) bsum[threadIdx.x] = s[threadIdx.x] - v;  // exclusive
}

__global__ void k_scan3(int* __restrict__ off, const int* __restrict__ cnt,
                        const int* __restrict__ bsum) {
  int gid = blockIdx.x * 1024 + threadIdx.x;
  if (gid < NSEG) off[gid] = off[gid] - cnt[gid] + bsum[blockIdx.x];
}

// ---------------- sbase: part[s][b] (in-place) -> off[b] + sum_{s'<s} part[s'][b] ----------------

__global__ void k_sbase(int* __restrict__ part, const int* __restrict__ off) {
  int b = blockIdx.x * 256 + threadIdx.x;
  if (b >= NSEG) return;
  int running = off[b];
  for (int s = 0; s < HSLICES; ++s) {
    size_t idx = (size_t)s * NSEG + b;
    int t = part[idx];
    part[idx] = running;
    running += t;
  }
}

// ---------------- fill: LDS-ranked, zero device atomics, NT scatter stores ----------------
// NT store on the scattered 4B csr writes skips L2 write-allocate -> no RMW line
// fetches (round-10 counters: 110 MB of FETCH was write-allocate).

__global__ __launch_bounds__(256) void k_fill3(const int* __restrict__ nidx,
                                               const int* __restrict__ eidx,
                                               const int* __restrict__ sbase,
                                               int* __restrict__ csr) {
  __shared__ int rank[6250];
  int r = blockIdx.x % NRANGES, s = blockIdx.x / NRANGES;
  const int *keys, *vals; int base, size, gbin_off;
  range_info(r, nidx, eidx, keys, vals, base, size, gbin_off);
  for (int i = threadIdx.x; i < size; i += 256) rank[i] = 0;
  __syncthreads();
  int lo = s * SLICE, hi = lo + SLICE;
  const int* sb = sbase + (size_t)s * NSEG + gbin_off;
  for (int i = lo + threadIdx.x; i < hi; i += 256) {
    int k = keys[i];
    unsigned d = (unsigned)(k - base);
    if (d < (unsigned)size) {
      int v = vals[i];
      int rk = atomicAdd(&rank[d], 1);
      __builtin_nontemporal_store(v, csr + sb[k] + rk);
    }
  }
}

// ---------------- x (f32) -> packed bf16 ----------------

__global__ void k_tobf(const float2* __restrict__ x2, unsigned* __restrict__ xbf) {
  int t = blockIdx.x * 256 + threadIdx.x;   // grid sized exactly
  float2 v = x2[t];
  xbf[t] = pack2(v.x, v.y);
}

// ---------------- gather node->edge, 128-wide bf16 table, one wave/edge, 8-deep ----------------

__global__ __launch_bounds__(256) void k_passAbf(const unsigned* __restrict__ tab,
                                                 const int* __restrict__ csr,
                                                 const int* __restrict__ off,
                                                 const int* __restrict__ cnt,
                                                 float* __restrict__ ebuf) {
  int wave = (blockIdx.x * blockDim.x + threadIdx.x) >> 6;
  int lane = threadIdx.x & 63;
  if (wave >= N_EDGES) return;
  int beg = off[wave];
  int m   = cnt[wave];
  const unsigned* src = tab + lane;
  float accx = 0.f, accy = 0.f;
  int idxv = 0;
  int j = 0;
  for (; j + 8 <= m; j += 8) {
    int jm = j & 63;
    if (jm == 0) {
      int p = j + lane;
      idxv = (p < m) ? __builtin_nontemporal_load(csr + beg + p) : 0;
    }
    int n0 = __shfl(idxv, jm);
    int n1 = __shfl(idxv, jm + 1);
    int n2 = __shfl(idxv, jm + 2);
    int n3 = __shfl(idxv, jm + 3);
    int n4 = __shfl(idxv, jm + 4);
    int n5 = __shfl(idxv, jm + 5);
    int n6 = __shfl(idxv, jm + 6);
    int n7 = __shfl(idxv, jm + 7);
    unsigned w0 = src[(size_t)n0 * 64];
    unsigned w1 = src[(size_t)n1 * 64];
    unsigned w2 = src[(size_t)n2 * 64];
    unsigned w3 = src[(size_t)n3 * 64];
    unsigned w4 = src[(size_t)n4 * 64];
    unsigned w5 = src[(size_t)n5 * 64];
    unsigned w6 = src[(size_t)n6 * 64];
    unsigned w7 = src[(size_t)n7 * 64];
    accx += ((bf_lo(w0) + bf_lo(w1)) + (bf_lo(w2) + bf_lo(w3))) +
            ((bf_lo(w4) + bf_lo(w5)) + (bf_lo(w6) + bf_lo(w7)));
    accy += ((bf_hi(w0) + bf_hi(w1)) + (bf_hi(w2) + bf_hi(w3))) +
            ((bf_hi(w4) + bf_hi(w5)) + (bf_hi(w6) + bf_hi(w7)));
  }
  for (; j < m; ++j) {
    int jm = j & 63;
    if (jm == 0) {
      int p = j + lane;
      idxv = (p < m) ? __builtin_nontemporal_load(csr + beg + p) : 0;
    }
    int n0 = __shfl(idxv, jm);
    unsigned w = src[(size_t)n0 * 64];
    accx += bf_lo(w); accy += bf_hi(w);
  }
  float binv = (m > 0) ? (1.f / (float)m) : 0.f;
  *reinterpret_cast<float2*>(ebuf + (size_t)wave * FIN + lane * 2) =
      make_float2(accx * binv, accy * binv);
}

// ---------------- edge GEMM: f32 A [20000][128] @ f32 W [128][128] -> packed bf16 Out ----------------

__global__ void k_gemm128b(const float* __restrict__ A, const float* __restrict__ W,
                           unsigned* __restrict__ Out) {
  __shared__ float As[64][33];
  __shared__ float Ws[32][128];
  int tid = threadIdx.x;
  int tx = tid % 16, ty = tid / 16;
  int row0 = blockIdx.x * 64;
  float acc[4][8];
#pragma unroll
  for (int i = 0; i < 4; ++i)
#pragma unroll
    for (int j = 0; j < 8; ++j) acc[i][j] = 0.f;

  for (int kc = 0; kc < FIN; kc += 32) {
    for (int i = tid; i < 64 * 32; i += 256) {
      int r = i >> 5, k = i & 31;
      int gr = row0 + r;
      As[r][k] = (gr < N_EDGES) ? A[(size_t)gr * FIN + kc + k] : 0.f;
    }
    for (int i = tid; i < 32 * 128; i += 256) {
      int k = i >> 7, cc = i & 127;
      Ws[k][cc] = W[(size_t)(kc + k) * 128 + cc];
    }
    __syncthreads();
#pragma unroll
    for (int k = 0; k < 32; ++k) {
      float a[4];
#pragma unroll
      for (int i = 0; i < 4; ++i) a[i] = As[ty * 4 + i][k];
      float w[8];
#pragma unroll
      for (int j = 0; j < 8; ++j) w[j] = Ws[k][tx * 8 + j];
#pragma unroll
      for (int i = 0; i < 4; ++i)
#pragma unroll
        for (int j = 0; j < 8; ++j) acc[i][j] += a[i] * w[j];
    }
    __syncthreads();
  }
#pragma unroll
  for (int i = 0; i < 4; ++i) {
    int gr = row0 + ty * 4 + i;
    if (gr < N_EDGES) {
#pragma unroll
      for (int jj = 0; jj < 4; ++jj)
        Out[(size_t)gr * 64 + tx * 4 + jj] = pack2(acc[i][2 * jj], acc[i][2 * jj + 1]);
    }
  }
}

// ---------------- gather edge->node, 128-wide bf16 table, +bias/relu, out packed bf16 h ----------------

template <bool RELU>
__global__ __launch_bounds__(256) void k_passBbf(const unsigned* __restrict__ tab,
                                                 const int* __restrict__ csr,
                                                 const int* __restrict__ off,
                                                 const int* __restrict__ cnt,
                                                 const float* __restrict__ bias,
                                                 unsigned* __restrict__ hbf) {
  int wave = (blockIdx.x * blockDim.x + threadIdx.x) >> 6;
  int lane = threadIdx.x & 63;
  if (wave >= N_NODES) return;
  int beg = off[N_EDGES + wave];
  int m   = cnt[N_EDGES + wave];
  const unsigned* src = tab + lane;
  float accx = 0.f, accy = 0.f;
  int idxv = 0;
  int j = 0;
  for (; j + 8 <= m; j += 8) {
    int jm = j & 63;
    if (jm == 0) {
      int p = j + lane;
      idxv = (p < m) ? __builtin_nontemporal_load(csr + beg + p) : 0;
    }
    int n0 = __shfl(idxv, jm);
    int n1 = __shfl(idxv, jm + 1);
    int n2 = __shfl(idxv, jm + 2);
    int n3 = __shfl(idxv, jm + 3);
    int n4 = __shfl(idxv, jm + 4);
    int n5 = __shfl(idxv, jm + 5);
    int n6 = __shfl(idxv, jm + 6);
    int n7 = __shfl(idxv, jm + 7);
    unsigned w0 = src[(size_t)n0 * 64];
    unsigned w1 = src[(size_t)n1 * 64];
    unsigned w2 = src[(size_t)n2 * 64];
    unsigned w3 = src[(size_t)n3 * 64];
    unsigned w4 = src[(size_t)n4 * 64];
    unsigned w5 = src[(size_t)n5 * 64];
    unsigned w6 = src[(size_t)n6 * 64];
    unsigned w7 = src[(size_t)n7 * 64];
    accx += ((bf_lo(w0) + bf_lo(w1)) + (bf_lo(w2) + bf_lo(w3))) +
            ((bf_lo(w4) + bf_lo(w5)) + (bf_lo(w6) + bf_lo(w7)));
    accy += ((bf_hi(w0) + bf_hi(w1)) + (bf_hi(w2) + bf_hi(w3))) +
            ((bf_hi(w4) + bf_hi(w5)) + (bf_hi(w6) + bf_hi(w7)));
  }
  for (; j < m; ++j) {
    int jm = j & 63;
    if (jm == 0) {
      int p = j + lane;
      idxv = (p < m) ? __builtin_nontemporal_load(csr + beg + p) : 0;
    }
    int n0 = __shfl(idxv, jm);
    unsigned w = src[(size_t)n0 * 64];
    accx += bf_lo(w); accy += bf_hi(w);
  }
  float dinv = (m > 0) ? (1.f / (float)m) : 0.f;
  float ox = accx * dinv + bias[lane * 2];
  float oy = accy * dinv + bias[lane * 2 + 1];
  if (RELU) { ox = fmaxf(ox, 0.f); oy = fmaxf(oy, 0.f); }
  hbf[(size_t)wave * 64 + lane] = pack2(ox, oy);
}

// ---------------- node GEMM (layer 3): bf16 h [100000][128] @ f32 W3 [128][64] -> packed bf16 ----------------
// 256 threads, 128x64 tile, A kept packed-bf16 in LDS (half the LDS traffic).

__global__ __launch_bounds__(256) void k_gemm_node_b(const unsigned* __restrict__ hbf,
                                                     const float* __restrict__ W,
                                                     unsigned* __restrict__ Out) {
  __shared__ unsigned Asp[128][17];   // 16 u32 words (32 k-vals) + pad
  __shared__ float Ws[32][64];
  int tid = threadIdx.x;
  int tx = tid & 15, ty = tid >> 4;   // tx: 16 col-groups of 4; ty: 16 row-groups of 8
  int row0 = blockIdx.x * 128;
  float acc[8][4];
#pragma unroll
  for (int i = 0; i < 8; ++i)
#pragma unroll
    for (int j = 0; j < 4; ++j) acc[i][j] = 0.f;

  for (int kc = 0; kc < FIN; kc += 32) {
    for (int i = tid; i < 128 * 16; i += 256) {
      int r = i >> 4, kp = i & 15;
      int gr = row0 + r;
      Asp[r][kp] = (gr < N_NODES) ? hbf[(size_t)gr * 64 + (kc >> 1) + kp] : 0u;
    }
    for (int i = tid; i < 32 * 64; i += 256) {
      int k = i >> 6, cc = i & 63;
      Ws[k][cc] = W[(size_t)(kc + k) * 64 + cc];
    }
    __syncthreads();
#pragma unroll
    for (int kp = 0; kp < 16; ++kp) {
      float alo[8], ahi[8];
#pragma unroll
      for (int i = 0; i < 8; ++i) {
        unsigned w = Asp[ty * 8 + i][kp];
        alo[i] = bf_lo(w); ahi[i] = bf_hi(w);
      }
      float w0[4], w1[4];
#pragma unroll
      for (int j = 0; j < 4; ++j) {
        w0[j] = Ws[2 * kp][tx * 4 + j];
        w1[j] = Ws[2 * kp + 1][tx * 4 + j];
      }
#pragma unroll
      for (int i = 0; i < 8; ++i)
#pragma unroll
        for (int j = 0; j < 4; ++j)
          acc[i][j] += alo[i] * w0[j] + ahi[i] * w1[j];
    }
    __syncthreads();
  }
#pragma unroll
  for (int i = 0; i < 8; ++i) {
    int gr = row0 + ty * 8 + i;
    if (gr < N_NODES) {
#pragma unroll
      for (int jj = 0; jj < 2; ++jj)
        Out[(size_t)gr * 32 + tx * 2 + jj] =
            pack2(acc[i][2 * jj], acc[i][2 * jj + 1]);
    }
  }
}

// ---------------- gather node->edge, 64-wide bf16 (ushort/lane), out bf16 ----------------

__global__ __launch_bounds__(256) void k_passA64b(const unsigned short* __restrict__ tab,
                                                  const int* __restrict__ csr,
                                                  const int* __restrict__ off,
                                                  const int* __restrict__ cnt,
                                                  unsigned short* __restrict__ eb3) {
  int wave = (blockIdx.x * blockDim.x + threadIdx.x) >> 6;
  int lane = threadIdx.x & 63;
  if (wave >= N_EDGES) return;
  int beg = off[wave];
  int m   = cnt[wave];
  const unsigned short* src = tab + lane;
  float acc = 0.f;
  int idxv = 0;
  int j = 0;
  for (; j + 8 <= m; j += 8) {
    int jm = j & 63;
    if (jm == 0) {
      int p = j + lane;
      idxv = (p < m) ? __builtin_nontemporal_load(csr + beg + p) : 0;
    }
    int n0 = __shfl(idxv, jm);
    int n1 = __shfl(idxv, jm + 1);
    int n2 = __shfl(idxv, jm + 2);
    int n3 = __shfl(idxv, jm + 3);
    int n4 = __shfl(idxv, jm + 4);
    int n5 = __shfl(idxv, jm + 5);
    int n6 = __shfl(idxv, jm + 6);
    int n7 = __shfl(idxv, jm + 7);
    float v0 = __uint_as_float((unsigned)src[(size_t)n0 * 64] << 16);
    float v1 = __uint_as_float((unsigned)src[(size_t)n1 * 64] << 16);
    float v2 = __uint_as_float((unsigned)src[(size_t)n2 * 64] << 16);
    float v3 = __uint_as_float((unsigned)src[(size_t)n3 * 64] << 16);
    float v4 = __uint_as_float((unsigned)src[(size_t)n4 * 64] << 16);
    float v5 = __uint_as_float((unsigned)src[(size_t)n5 * 64] << 16);
    float v6 = __uint_as_float((unsigned)src[(size_t)n6 * 64] << 16);
    float v7 = __uint_as_float((unsigned)src[(size_t)n7 * 64] << 16);
    acc += ((v0 + v1) + (v2 + v3)) + ((v4 + v5) + (v6 + v7));
  }
  for (; j < m; ++j) {
    int jm = j & 63;
    if (jm == 0) {
      int p = j + lane;
      idxv = (p < m) ? __builtin_nontemporal_load(csr + beg + p) : 0;
    }
    int n0 = __shfl(idxv, jm);
    acc += __uint_as_float((unsigned)src[(size_t)n0 * 64] << 16);
  }
  float binv = (m > 0) ? (1.f / (float)m) : 0.f;
  eb3[(size_t)wave * 64 + lane] = f2bf(acc * binv);
}

// ---------------- gather edge->node, 64-wide bf16 table (2.56 MB), out f32 ----------------

__global__ __launch_bounds__(256) void k_passB64b(const unsigned short* __restrict__ tab,
                                                  const int* __restrict__ csr,
                                                  const int* __restrict__ off,
                                                  const int* __restrict__ cnt,
                                                  const float* __restrict__ bias,
                                                  float* __restrict__ out) {
  int wave = (blockIdx.x * blockDim.x + threadIdx.x) >> 6;
  int lane = threadIdx.x & 63;
  if (wave >= N_NODES) return;
  int beg = off[N_EDGES + wave];
  int m   = cnt[N_EDGES + wave];
  const unsigned short* src = tab + lane;
  float acc = 0.f;
  int idxv = 0;
  int j = 0;
  for (; j + 8 <= m; j += 8) {
    int jm = j & 63;
    if (jm == 0) {
      int p = j + lane;
      idxv = (p < m) ? __builtin_nontemporal_load(csr + beg + p) : 0;
    }
    int n0 = __shfl(idxv, jm);
    int n1 = __shfl(idxv, jm + 1);
    int n2 = __shfl(idxv, jm + 2);
    int n3 = __shfl(idxv, jm + 3);
    int n4 = __shfl(idxv, jm + 4);
    int n5 = __shfl(idxv, jm + 5);
    int n6 = __shfl(idxv, jm + 6);
    int n7 = __shfl(idxv, jm + 7);
    float v0 = __uint_as_float((unsigned)src[(size_t)n0 * 64] << 16);
    float v1 = __uint_as_float((unsigned)src[(size_t)n1 * 64] << 16);
    float v2 = __uint_as_float((unsigned)src[(size_t)n2 * 64] << 16);
    float v3 = __uint_as_float((unsigned)src[(size_t)n3 * 64] << 16);
    float v4 = __uint_as_float((unsigned)src[(size_t)n4 * 64] << 16);
    float v5 = __uint_as_float((unsigned)src[(size_t)n5 * 64] << 16);
    float v6 = __uint_as_float((unsigned)src[(size_t)n6 * 64] << 16);
    float v7 = __uint_as_float((unsigned)src[(size_t)n7 * 64] << 16);
    acc += ((v0 + v1) + (v2 + v3)) + ((v4 + v5) + (v6 + v7));
  }
  for (; j < m; ++j) {
    int jm = j & 63;
    if (jm == 0) {
      int p = j + lane;
      idxv = (p < m) ? __builtin_nontemporal_load(csr + beg + p) : 0;
    }
    int n0 = __shfl(idxv, jm);
    acc += __uint_as_float((unsigned)src[(size_t)n0 * 64] << 16);
  }
  float dinv = (m > 0) ? (1.f / (float)m) : 0.f;
  out[(size_t)wave * 64 + lane] = acc * dinv + bias[lane];
}

// ---------------- launch ----------------

extern "C" void kernel_launch(void* const* d_in, const int* in_sizes, int n_in,
                              void* d_out, int out_size, void* d_ws, size_t ws_size,
                              hipStream_t stream) {
  const float* x  = (const float*)d_in[0];
  const float* W1 = (const float*)d_in[1];
  const float* b1 = (const float*)d_in[2];
  const float* W2 = (const float*)d_in[3];
  const float* b2 = (const float*)d_in[4];
  const float* W3 = (const float*)d_in[5];
  const float* b3 = (const float*)d_in[6];
  const int* nidx = (const int*)d_in[7];
  const int* eidx = (const int*)d_in[8];

  // workspace layout (bytes)
  const size_t OFF_CNT  = 0;          // int[120000]
  const size_t OFF_OFF  = 480000;     // int[120000]
  const size_t OFF_BSUM = 1440000;    // int[128]
  const size_t OFF_CSR  = 1441792;    // int[3200000]            (12.8 MB)
  const size_t OFF_EB   = 14241792;   // f32[20000*128] 10.24 MB
  const size_t OFF_EB2  = 24481792;   // u32[20000*64]  5.12 MB  (bf16 edge feats) ; layer-3 eb3 aliases EB
  const size_t OFF_XBF  = 29601792;   // u32[100000*64] 25.6 MB  (bf16 x) ; part[64][NSEG]=30.72MB aliases
  const size_t OFF_HBF  = 55201792;   //   XBF..XBF+30.72MB (dead before k_tobf / layer-1 passBbf)
  const size_t NEEDED   = 80801792;
  if (ws_size < NEEDED) return;

  char* ws = (char*)d_ws;
  int*      cnt   = (int*)(ws + OFF_CNT);
  int*      off   = (int*)(ws + OFF_OFF);
  int*      bsum  = (int*)(ws + OFF_BSUM);
  int*      csr   = (int*)(ws + OFF_CSR);
  int*      part  = (int*)(ws + OFF_XBF);    // 64*120000*4 = 30.72 MB, dead after k_fill3
  float*    ebuf  = (float*)(ws + OFF_EB);   // f32 edge agg (layers 1-2)
  unsigned* eb2bf = (unsigned*)(ws + OFF_EB2);
  unsigned* xbf   = (unsigned*)(ws + OFF_XBF);
  unsigned* hw3   = (unsigned*)(ws + OFF_XBF);          // layer 3: h@W3, packed bf16 [100000][32 u32]
  unsigned short* eb3 = (unsigned short*)(ws + OFF_EB); // layer 3: edge agg bf16 [20000][64]
  unsigned* hbf   = (unsigned*)(ws + OFF_HBF);
  float*    out   = (float*)d_out;

  hipMemsetAsync(ws + OFF_BSUM, 0, 512, stream);  // bsum

  // CSR build — zero device-scope atomics
  k_hist<<<NRANGES * HSLICES, 256, 0, stream>>>(nidx, eidx, part);       // 1280 blocks
  k_hreduce<<<(NSEG + 255) / 256, 256, 0, stream>>>(part, cnt);
  const int nb = (NSEG + 1023) / 1024;  // 118
  k_scan1<<<nb, 1024, 0, stream>>>(cnt, off, bsum);
  k_scan2<<<1, 128, 0, stream>>>(bsum, nb);
  k_scan3<<<nb, 1024, 0, stream>>>(off, cnt, bsum);
  k_sbase<<<(NSEG + 255) / 256, 256, 0, stream>>>(part, off);
  k_fill3<<<NRANGES * HSLICES, 256, 0, stream>>>(nidx, eidx, part, csr); // 1280 blocks

  // x -> bf16 (6.4M packed words) — must run after k_fill3 (part aliases xbf)
  k_tobf<<<25000, 256, 0, stream>>>((const float2*)x, xbf);

  const int BLK_A = (N_EDGES * 64 + 255) / 256;   // 5000
  const int BLK_B = (N_NODES * 64 + 255) / 256;   // 25000
  const int BLK_G = (N_EDGES + 63) / 64;          // 313
  const int BLK_GN = (N_NODES + 127) / 128;       // 782

  // layer 1: x -> h (relu)
  k_passAbf<<<BLK_A, 256, 0, stream>>>(xbf, csr, off, cnt, ebuf);
  k_gemm128b<<<BLK_G, 256, 0, stream>>>(ebuf, W1, eb2bf);
  k_passBbf<true><<<BLK_B, 256, 0, stream>>>(eb2bf, csr, off, cnt, b1, hbf);

  // layer 2: h -> h (relu)
  k_passAbf<<<BLK_A, 256, 0, stream>>>(hbf, csr, off, cnt, ebuf);
  k_gemm128b<<<BLK_G, 256, 0, stream>>>(ebuf, W2, eb2bf);
  k_passBbf<true><<<BLK_B, 256, 0, stream>>>(eb2bf, csr, off, cnt, b2, hbf);

  // layer 3: node-GEMM first, then 64-wide gathers
  k_gemm_node_b<<<BLK_GN, 256, 0, stream>>>(hbf, W3, hw3);
  k_passA64b<<<BLK_A, 256, 0, stream>>>((const unsigned short*)hw3, csr, off, cnt, eb3);
  k_passB64b<<<BLK_B, 256, 0, stream>>>(eb3, csr, off, cnt, b3, out);
}

// Round 12
// 620.124 us; speedup vs baseline: 1.0693x; 1.0693x over previous
//
#include <hip/hip_runtime.h>

#define N_NODES 100000
#define N_EDGES 20000
#define NNZV    1600000
#define NSEG    (N_EDGES + N_NODES)
#define FIN     128
#define HSLICES 64
#define SLICE   (NNZV / HSLICES)    // 25000
#define NR_E    4                   // hist: edge ranges of 5000
#define NR_N    16                  // hist: node ranges of 6250
#define NRANGES (NR_E + NR_N)       // 20 (hist decomposition)

// ---- bf16 helpers (RTNE pack, cheap unpack) ----
__device__ __forceinline__ unsigned short f2bf(float f) {
  unsigned u = __float_as_uint(f);
  unsigned r = u + 0x7fffu + ((u >> 16) & 1u);
  return (unsigned short)(r >> 16);
}
__device__ __forceinline__ unsigned pack2(float lo, float hi) {
  return (unsigned)f2bf(lo) | ((unsigned)f2bf(hi) << 16);
}
__device__ __forceinline__ float bf_lo(unsigned w) { return __uint_as_float(w << 16); }
__device__ __forceinline__ float bf_hi(unsigned w) { return __uint_as_float(w & 0xffff0000u); }

// hist range decomposition (20 ranges)
__device__ __forceinline__ void range_info(int r, const int* nidx, const int* eidx,
                                           const int*& keys, int& base, int& size, int& gbin_off) {
  if (r < NR_E) { keys = eidx; base = r * 5000; size = 5000; gbin_off = 0; }
  else { keys = nidx; base = (r - NR_E) * 6250; size = 6250; gbin_off = N_EDGES; }
}

// ---------------- histogram count: part[s][bin], LDS, no device atomics ----------------

__global__ __launch_bounds__(256) void k_hist(const int* __restrict__ nidx,
                                              const int* __restrict__ eidx,
                                              int* __restrict__ part) {
  __shared__ int hist[6250];
  int r = blockIdx.x % NRANGES, s = blockIdx.x / NRANGES;
  const int* keys; int base, size, gbin_off;
  range_info(r, nidx, eidx, keys, base, size, gbin_off);
  for (int i = threadIdx.x; i < size; i += 256) hist[i] = 0;
  __syncthreads();
  int lo = s * SLICE, hi = lo + SLICE;
  for (int i = lo + threadIdx.x; i < hi; i += 256) {
    int k = keys[i];
    unsigned d = (unsigned)(k - base);
    if (d < (unsigned)size) atomicAdd(&hist[d], 1);
  }
  __syncthreads();
  int* dst = part + (size_t)s * NSEG + gbin_off + base;
  for (int i = threadIdx.x; i < size; i += 256) dst[i] = hist[i];
}

__global__ void k_hreduce(const int* __restrict__ part, int* __restrict__ cnt) {
  int b = blockIdx.x * 256 + threadIdx.x;
  if (b >= NSEG) return;
  int sum = 0;
  for (int s = 0; s < HSLICES; ++s) sum += part[(size_t)s * NSEG + b];
  cnt[b] = sum;
}

// ---------------- scans ----------------

__global__ void k_scan1(const int* __restrict__ cnt, int* __restrict__ incl,
                        int* __restrict__ bsum) {
  __shared__ int s[1024];
  int gid = blockIdx.x * 1024 + threadIdx.x;
  int v = (gid < NSEG) ? cnt[gid] : 0;
  s[threadIdx.x] = v;
  __syncthreads();
  for (int d = 1; d < 1024; d <<= 1) {
    int t = (threadIdx.x >= d) ? s[threadIdx.x - d] : 0;
    __syncthreads();
    s[threadIdx.x] += t;
    __syncthreads();
  }
  if (gid < NSEG) incl[gid] = s[threadIdx.x];
  if (threadIdx.x == 1023) bsum[blockIdx.x] = s[1023];
}

__global__ void k_scan2(int* __restrict__ bsum, int nb) {
  __shared__ int s[128];
  int v = (threadIdx.x < nb) ? bsum[threadIdx.x] : 0;
  s[threadIdx.x] = v;
  __syncthreads();
  for (int d = 1; d < 128; d <<= 1) {
    int t = (threadIdx.x >= (unsigned)d) ? s[threadIdx.x - d] : 0;
    __syncthreads();
    s[threadIdx.x] += t;
    __syncthreads();
  }
  if (threadIdx.x < nb) bsum[threadIdx.x] = s[threadIdx.x] - v;  // exclusive
}

__global__ void k_scan3(int* __restrict__ off, const int* __restrict__ cnt,
                        const int* __restrict__ bsum) {
  int gid = blockIdx.x * 1024 + threadIdx.x;
  if (gid < NSEG) off[gid] = off[gid] - cnt[gid] + bsum[blockIdx.x];
}

// ---------------- sbase: part[s][b] (in-place) -> off[b] + sum_{s'<s} part[s'][b] ----------------

__global__ void k_sbase(int* __restrict__ part, const int* __restrict__ off) {
  int b = blockIdx.x * 256 + threadIdx.x;
  if (b >= NSEG) return;
  int running = off[b];
  for (int s = 0; s < HSLICES; ++s) {
    size_t idx = (size_t)s * NSEG + b;
    int t = part[idx];
    part[idx] = running;
    running += t;
  }
}

// ---------------- fill: LDS-ranked, zero device atomics, XCD-pinned ranges ----------------
// 24 ranges (8 edge x 2500, 16 node x 6250) x 64 slices = 1536 blocks.
// Range r is handled only by blocks with blockIdx%8 == r%8, so each CSR region
// is written by one XCD -> lines assemble in that XCD's L2, no cross-XCD RMW.

__global__ __launch_bounds__(256) void k_fill3(const int* __restrict__ nidx,
                                               const int* __restrict__ eidx,
                                               const int* __restrict__ sbase,
                                               int* __restrict__ csr) {
  __shared__ int rank[6250];
  int g = blockIdx.x;
  int xcd = g & 7;
  int i2 = g >> 3;            // 0..191
  int li = i2 % 3;            // local range index
  int s  = i2 / 3;            // slice 0..63
  int r  = li * 8 + xcd;      // 0..23
  const int *keys, *vals; int base, size, gbin_off;
  if (r < 8) { keys = eidx; vals = nidx; base = r * 2500; size = 2500; gbin_off = 0; }
  else { keys = nidx; vals = eidx; base = (r - 8) * 6250; size = 6250; gbin_off = N_EDGES; }
  for (int i = threadIdx.x; i < size; i += 256) rank[i] = 0;
  __syncthreads();
  int lo = s * SLICE, hi = lo + SLICE;
  const int* sb = sbase + (size_t)s * NSEG + gbin_off;
  for (int i = lo + threadIdx.x; i < hi; i += 256) {
    int k = keys[i];
    unsigned d = (unsigned)(k - base);
    if (d < (unsigned)size) {
      int v = vals[i];
      int rk = atomicAdd(&rank[d], 1);
      csr[sb[k] + rk] = v;
    }
  }
}

// ---------------- x (f32) -> packed bf16 ----------------

__global__ void k_tobf(const float2* __restrict__ x2, unsigned* __restrict__ xbf) {
  int t = blockIdx.x * 256 + threadIdx.x;   // grid sized exactly
  float2 v = x2[t];
  xbf[t] = pack2(v.x, v.y);
}

// ---------------- gather node->edge, 128-wide bf16 table, one wave/edge, 8-deep ----------------
// Output: packed bf16 edge aggregates [20000][64 u32].

__global__ __launch_bounds__(256) void k_passAbf(const unsigned* __restrict__ tab,
                                                 const int* __restrict__ csr,
                                                 const int* __restrict__ off,
                                                 const int* __restrict__ cnt,
                                                 unsigned* __restrict__ ebuf) {
  int wave = (blockIdx.x * blockDim.x + threadIdx.x) >> 6;
  int lane = threadIdx.x & 63;
  if (wave >= N_EDGES) return;
  int beg = off[wave];
  int m   = cnt[wave];
  const unsigned* src = tab + lane;
  float accx = 0.f, accy = 0.f;
  int idxv = 0;
  int j = 0;
  for (; j + 8 <= m; j += 8) {
    int jm = j & 63;
    if (jm == 0) {
      int p = j + lane;
      idxv = (p < m) ? __builtin_nontemporal_load(csr + beg + p) : 0;
    }
    int n0 = __shfl(idxv, jm);
    int n1 = __shfl(idxv, jm + 1);
    int n2 = __shfl(idxv, jm + 2);
    int n3 = __shfl(idxv, jm + 3);
    int n4 = __shfl(idxv, jm + 4);
    int n5 = __shfl(idxv, jm + 5);
    int n6 = __shfl(idxv, jm + 6);
    int n7 = __shfl(idxv, jm + 7);
    unsigned w0 = src[(size_t)n0 * 64];
    unsigned w1 = src[(size_t)n1 * 64];
    unsigned w2 = src[(size_t)n2 * 64];
    unsigned w3 = src[(size_t)n3 * 64];
    unsigned w4 = src[(size_t)n4 * 64];
    unsigned w5 = src[(size_t)n5 * 64];
    unsigned w6 = src[(size_t)n6 * 64];
    unsigned w7 = src[(size_t)n7 * 64];
    accx += ((bf_lo(w0) + bf_lo(w1)) + (bf_lo(w2) + bf_lo(w3))) +
            ((bf_lo(w4) + bf_lo(w5)) + (bf_lo(w6) + bf_lo(w7)));
    accy += ((bf_hi(w0) + bf_hi(w1)) + (bf_hi(w2) + bf_hi(w3))) +
            ((bf_hi(w4) + bf_hi(w5)) + (bf_hi(w6) + bf_hi(w7)));
  }
  for (; j < m; ++j) {
    int jm = j & 63;
    if (jm == 0) {
      int p = j + lane;
      idxv = (p < m) ? __builtin_nontemporal_load(csr + beg + p) : 0;
    }
    int n0 = __shfl(idxv, jm);
    unsigned w = src[(size_t)n0 * 64];
    accx += bf_lo(w); accy += bf_hi(w);
  }
  float binv = (m > 0) ? (1.f / (float)m) : 0.f;
  ebuf[(size_t)wave * 64 + lane] = pack2(accx * binv, accy * binv);
}

// ---------------- edge GEMM: bf16 A [20000][128] @ f32 W [128][128] -> packed bf16 Out ----------------
// A kept packed-bf16 in LDS (pattern validated by round-10 gemm_node_b).

__global__ __launch_bounds__(256) void k_gemm128b(const unsigned* __restrict__ Abf,
                                                  const float* __restrict__ W,
                                                  unsigned* __restrict__ Out) {
  __shared__ unsigned Asp[64][17];
  __shared__ float Ws[32][128];
  int tid = threadIdx.x;
  int tx = tid % 16, ty = tid / 16;
  int row0 = blockIdx.x * 64;
  float acc[4][8];
#pragma unroll
  for (int i = 0; i < 4; ++i)
#pragma unroll
    for (int j = 0; j < 8; ++j) acc[i][j] = 0.f;

  for (int kc = 0; kc < FIN; kc += 32) {
    for (int i = tid; i < 64 * 16; i += 256) {
      int r = i >> 4, kp = i & 15;
      int gr = row0 + r;
      Asp[r][kp] = (gr < N_EDGES) ? Abf[(size_t)gr * 64 + (kc >> 1) + kp] : 0u;
    }
    for (int i = tid; i < 32 * 128; i += 256) {
      int k = i >> 7, cc = i & 127;
      Ws[k][cc] = W[(size_t)(kc + k) * 128 + cc];
    }
    __syncthreads();
#pragma unroll
    for (int kp = 0; kp < 16; ++kp) {
      float alo[4], ahi[4];
#pragma unroll
      for (int i = 0; i < 4; ++i) {
        unsigned w = Asp[ty * 4 + i][kp];
        alo[i] = bf_lo(w); ahi[i] = bf_hi(w);
      }
      float w0[8], w1[8];
#pragma unroll
      for (int j = 0; j < 8; ++j) {
        w0[j] = Ws[2 * kp][tx * 8 + j];
        w1[j] = Ws[2 * kp + 1][tx * 8 + j];
      }
#pragma unroll
      for (int i = 0; i < 4; ++i)
#pragma unroll
        for (int j = 0; j < 8; ++j)
          acc[i][j] += alo[i] * w0[j] + ahi[i] * w1[j];
    }
    __syncthreads();
  }
#pragma unroll
  for (int i = 0; i < 4; ++i) {
    int gr = row0 + ty * 4 + i;
    if (gr < N_EDGES) {
#pragma unroll
      for (int jj = 0; jj < 4; ++jj)
        Out[(size_t)gr * 64 + tx * 4 + jj] = pack2(acc[i][2 * jj], acc[i][2 * jj + 1]);
    }
  }
}

// ---------------- gather edge->node, 128-wide bf16 table, +bias/relu, out packed bf16 h ----------------

template <bool RELU>
__global__ __launch_bounds__(256) void k_passBbf(const unsigned* __restrict__ tab,
                                                 const int* __restrict__ csr,
                                                 const int* __restrict__ off,
                                                 const int* __restrict__ cnt,
                                                 const float* __restrict__ bias,
                                                 unsigned* __restrict__ hbf) {
  int wave = (blockIdx.x * blockDim.x + threadIdx.x) >> 6;
  int lane = threadIdx.x & 63;
  if (wave >= N_NODES) return;
  int beg = off[N_EDGES + wave];
  int m   = cnt[N_EDGES + wave];
  const unsigned* src = tab + lane;
  float accx = 0.f, accy = 0.f;
  int idxv = 0;
  int j = 0;
  for (; j + 8 <= m; j += 8) {
    int jm = j & 63;
    if (jm == 0) {
      int p = j + lane;
      idxv = (p < m) ? __builtin_nontemporal_load(csr + beg + p) : 0;
    }
    int n0 = __shfl(idxv, jm);
    int n1 = __shfl(idxv, jm + 1);
    int n2 = __shfl(idxv, jm + 2);
    int n3 = __shfl(idxv, jm + 3);
    int n4 = __shfl(idxv, jm + 4);
    int n5 = __shfl(idxv, jm + 5);
    int n6 = __shfl(idxv, jm + 6);
    int n7 = __shfl(idxv, jm + 7);
    unsigned w0 = src[(size_t)n0 * 64];
    unsigned w1 = src[(size_t)n1 * 64];
    unsigned w2 = src[(size_t)n2 * 64];
    unsigned w3 = src[(size_t)n3 * 64];
    unsigned w4 = src[(size_t)n4 * 64];
    unsigned w5 = src[(size_t)n5 * 64];
    unsigned w6 = src[(size_t)n6 * 64];
    unsigned w7 = src[(size_t)n7 * 64];
    accx += ((bf_lo(w0) + bf_lo(w1)) + (bf_lo(w2) + bf_lo(w3))) +
            ((bf_lo(w4) + bf_lo(w5)) + (bf_lo(w6) + bf_lo(w7)));
    accy += ((bf_hi(w0) + bf_hi(w1)) + (bf_hi(w2) + bf_hi(w3))) +
            ((bf_hi(w4) + bf_hi(w5)) + (bf_hi(w6) + bf_hi(w7)));
  }
  for (; j < m; ++j) {
    int jm = j & 63;
    if (jm == 0) {
      int p = j + lane;
      idxv = (p < m) ? __builtin_nontemporal_load(csr + beg + p) : 0;
    }
    int n0 = __shfl(idxv, jm);
    unsigned w = src[(size_t)n0 * 64];
    accx += bf_lo(w); accy += bf_hi(w);
  }
  float dinv = (m > 0) ? (1.f / (float)m) : 0.f;
  float ox = accx * dinv + bias[lane * 2];
  float oy = accy * dinv + bias[lane * 2 + 1];
  if (RELU) { ox = fmaxf(ox, 0.f); oy = fmaxf(oy, 0.f); }
  hbf[(size_t)wave * 64 + lane] = pack2(ox, oy);
}

// ---------------- node GEMM (layer 3): bf16 h [100000][128] @ f32 W3 [128][64] -> packed bf16 ----------------
// (round-10 known-good version)

__global__ void k_gemm_node_b(const unsigned* __restrict__ hbf, const float* __restrict__ W,
                              unsigned* __restrict__ Out) {
  __shared__ float As[64][33];
  __shared__ float Ws[32][64];
  int tid = threadIdx.x;            // 128 threads
  int tx = tid % 8, ty = tid / 8;
  int row0 = blockIdx.x * 64;
  float acc[4][8];
#pragma unroll
  for (int i = 0; i < 4; ++i)
#pragma unroll
    for (int j = 0; j < 8; ++j) acc[i][j] = 0.f;

  for (int kc = 0; kc < FIN; kc += 32) {
    for (int i = tid; i < 64 * 16; i += 128) {
      int r = i >> 4, kp = i & 15;
      int gr = row0 + r;
      unsigned w = (gr < N_NODES) ? hbf[(size_t)gr * 64 + (kc >> 1) + kp] : 0u;
      As[r][2 * kp]     = bf_lo(w);
      As[r][2 * kp + 1] = bf_hi(w);
    }
    for (int i = tid; i < 32 * 64; i += 128) {
      int k = i >> 6, cc = i & 63;
      Ws[k][cc] = W[(size_t)(kc + k) * 64 + cc];
    }
    __syncthreads();
#pragma unroll
    for (int k = 0; k < 32; ++k) {
      float a[4];
#pragma unroll
      for (int i = 0; i < 4; ++i) a[i] = As[ty * 4 + i][k];
      float w[8];
#pragma unroll
      for (int j = 0; j < 8; ++j) w[j] = Ws[k][tx * 8 + j];
#pragma unroll
      for (int i = 0; i < 4; ++i)
#pragma unroll
        for (int j = 0; j < 8; ++j) acc[i][j] += a[i] * w[j];
    }
    __syncthreads();
  }
#pragma unroll
  for (int i = 0; i < 4; ++i) {
    int gr = row0 + ty * 4 + i;
    if (gr < N_NODES) {
#pragma unroll
      for (int jj = 0; jj < 4; ++jj)
        Out[(size_t)gr * 32 + tx * 4 + jj] = pack2(acc[i][2 * jj], acc[i][2 * jj + 1]);
    }
  }
}

// ---------------- gather node->edge, 64-wide bf16 (ushort/lane), out bf16 ----------------

__global__ __launch_bounds__(256) void k_passA64b(const unsigned short* __restrict__ tab,
                                                  const int* __restrict__ csr,
                                                  const int* __restrict__ off,
                                                  const int* __restrict__ cnt,
                                                  unsigned short* __restrict__ eb3) {
  int wave = (blockIdx.x * blockDim.x + threadIdx.x) >> 6;
  int lane = threadIdx.x & 63;
  if (wave >= N_EDGES) return;
  int beg = off[wave];
  int m   = cnt[wave];
  const unsigned short* src = tab + lane;
  float acc = 0.f;
  int idxv = 0;
  int j = 0;
  for (; j + 8 <= m; j += 8) {
    int jm = j & 63;
    if (jm == 0) {
      int p = j + lane;
      idxv = (p < m) ? __builtin_nontemporal_load(csr + beg + p) : 0;
    }
    int n0 = __shfl(idxv, jm);
    int n1 = __shfl(idxv, jm + 1);
    int n2 = __shfl(idxv, jm + 2);
    int n3 = __shfl(idxv, jm + 3);
    int n4 = __shfl(idxv, jm + 4);
    int n5 = __shfl(idxv, jm + 5);
    int n6 = __shfl(idxv, jm + 6);
    int n7 = __shfl(idxv, jm + 7);
    float v0 = __uint_as_float((unsigned)src[(size_t)n0 * 64] << 16);
    float v1 = __uint_as_float((unsigned)src[(size_t)n1 * 64] << 16);
    float v2 = __uint_as_float((unsigned)src[(size_t)n2 * 64] << 16);
    float v3 = __uint_as_float((unsigned)src[(size_t)n3 * 64] << 16);
    float v4 = __uint_as_float((unsigned)src[(size_t)n4 * 64] << 16);
    float v5 = __uint_as_float((unsigned)src[(size_t)n5 * 64] << 16);
    float v6 = __uint_as_float((unsigned)src[(size_t)n6 * 64] << 16);
    float v7 = __uint_as_float((unsigned)src[(size_t)n7 * 64] << 16);
    acc += ((v0 + v1) + (v2 + v3)) + ((v4 + v5) + (v6 + v7));
  }
  for (; j < m; ++j) {
    int jm = j & 63;
    if (jm == 0) {
      int p = j + lane;
      idxv = (p < m) ? __builtin_nontemporal_load(csr + beg + p) : 0;
    }
    int n0 = __shfl(idxv, jm);
    acc += __uint_as_float((unsigned)src[(size_t)n0 * 64] << 16);
  }
  float binv = (m > 0) ? (1.f / (float)m) : 0.f;
  eb3[(size_t)wave * 64 + lane] = f2bf(acc * binv);
}

// ---------------- gather edge->node, 64-wide bf16 table (2.56 MB), out f32 ----------------

__global__ __launch_bounds__(256) void k_passB64b(const unsigned short* __restrict__ tab,
                                                  const int* __restrict__ csr,
                                                  const int* __restrict__ off,
                                                  const int* __restrict__ cnt,
                                                  const float* __restrict__ bias,
                                                  float* __restrict__ out) {
  int wave = (blockIdx.x * blockDim.x + threadIdx.x) >> 6;
  int lane = threadIdx.x & 63;
  if (wave >= N_NODES) return;
  int beg = off[N_EDGES + wave];
  int m   = cnt[N_EDGES + wave];
  const unsigned short* src = tab + lane;
  float acc = 0.f;
  int idxv = 0;
  int j = 0;
  for (; j + 8 <= m; j += 8) {
    int jm = j & 63;
    if (jm == 0) {
      int p = j + lane;
      idxv = (p < m) ? __builtin_nontemporal_load(csr + beg + p) : 0;
    }
    int n0 = __shfl(idxv, jm);
    int n1 = __shfl(idxv, jm + 1);
    int n2 = __shfl(idxv, jm + 2);
    int n3 = __shfl(idxv, jm + 3);
    int n4 = __shfl(idxv, jm + 4);
    int n5 = __shfl(idxv, jm + 5);
    int n6 = __shfl(idxv, jm + 6);
    int n7 = __shfl(idxv, jm + 7);
    float v0 = __uint_as_float((unsigned)src[(size_t)n0 * 64] << 16);
    float v1 = __uint_as_float((unsigned)src[(size_t)n1 * 64] << 16);
    float v2 = __uint_as_float((unsigned)src[(size_t)n2 * 64] << 16);
    float v3 = __uint_as_float((unsigned)src[(size_t)n3 * 64] << 16);
    float v4 = __uint_as_float((unsigned)src[(size_t)n4 * 64] << 16);
    float v5 = __uint_as_float((unsigned)src[(size_t)n5 * 64] << 16);
    float v6 = __uint_as_float((unsigned)src[(size_t)n6 * 64] << 16);
    float v7 = __uint_as_float((unsigned)src[(size_t)n7 * 64] << 16);
    acc += ((v0 + v1) + (v2 + v3)) + ((v4 + v5) + (v6 + v7));
  }
  for (; j < m; ++j) {
    int jm = j & 63;
    if (jm == 0) {
      int p = j + lane;
      idxv = (p < m) ? __builtin_nontemporal_load(csr + beg + p) : 0;
    }
    int n0 = __shfl(idxv, jm);
    acc += __uint_as_float((unsigned)src[(size_t)n0 * 64] << 16);
  }
  float dinv = (m > 0) ? (1.f / (float)m) : 0.f;
  out[(size_t)wave * 64 + lane] = acc * dinv + bias[lane];
}

// ---------------- launch ----------------

extern "C" void kernel_launch(void* const* d_in, const int* in_sizes, int n_in,
                              void* d_out, int out_size, void* d_ws, size_t ws_size,
                              hipStream_t stream) {
  const float* x  = (const float*)d_in[0];
  const float* W1 = (const float*)d_in[1];
  const float* b1 = (const float*)d_in[2];
  const float* W2 = (const float*)d_in[3];
  const float* b2 = (const float*)d_in[4];
  const float* W3 = (const float*)d_in[5];
  const float* b3 = (const float*)d_in[6];
  const int* nidx = (const int*)d_in[7];
  const int* eidx = (const int*)d_in[8];

  // workspace layout (bytes)
  const size_t OFF_CNT  = 0;          // int[120000]
  const size_t OFF_OFF  = 480000;     // int[120000]
  const size_t OFF_BSUM = 1440000;    // int[128]
  const size_t OFF_CSR  = 1441792;    // int[3200000]            (12.8 MB)
  const size_t OFF_EB   = 14241792;   // u32[20000*64] 5.12 MB (bf16 edge agg) ; eb3 aliases
  const size_t OFF_EB2  = 24481792;   // u32[20000*64] 5.12 MB (bf16 edge feats)
  const size_t OFF_XBF  = 29601792;   // u32[100000*64] 25.6 MB (bf16 x) ; part[64][NSEG]=30.72MB aliases
  const size_t OFF_HBF  = 55201792;   //   XBF..XBF+30.72MB (dead before k_tobf / layer-1 passBbf)
  const size_t NEEDED   = 80801792;
  if (ws_size < NEEDED) return;

  char* ws = (char*)d_ws;
  int*      cnt   = (int*)(ws + OFF_CNT);
  int*      off   = (int*)(ws + OFF_OFF);
  int*      bsum  = (int*)(ws + OFF_BSUM);
  int*      csr   = (int*)(ws + OFF_CSR);
  int*      part  = (int*)(ws + OFF_XBF);    // 64*120000*4 = 30.72 MB, dead after k_fill3
  unsigned* ebuf  = (unsigned*)(ws + OFF_EB);// bf16 edge agg (layers 1-2)
  unsigned* eb2bf = (unsigned*)(ws + OFF_EB2);
  unsigned* xbf   = (unsigned*)(ws + OFF_XBF);
  unsigned* hw3   = (unsigned*)(ws + OFF_XBF);          // layer 3: h@W3, packed bf16 [100000][32 u32]
  unsigned short* eb3 = (unsigned short*)(ws + OFF_EB); // layer 3: edge agg bf16 [20000][64]
  unsigned* hbf   = (unsigned*)(ws + OFF_HBF);
  float*    out   = (float*)d_out;

  hipMemsetAsync(ws + OFF_BSUM, 0, 512, stream);  // bsum

  // CSR build — zero device-scope atomics
  k_hist<<<NRANGES * HSLICES, 256, 0, stream>>>(nidx, eidx, part);       // 1280 blocks
  k_hreduce<<<(NSEG + 255) / 256, 256, 0, stream>>>(part, cnt);
  const int nb = (NSEG + 1023) / 1024;  // 118
  k_scan1<<<nb, 1024, 0, stream>>>(cnt, off, bsum);
  k_scan2<<<1, 128, 0, stream>>>(bsum, nb);
  k_scan3<<<nb, 1024, 0, stream>>>(off, cnt, bsum);
  k_sbase<<<(NSEG + 255) / 256, 256, 0, stream>>>(part, off);
  k_fill3<<<24 * HSLICES, 256, 0, stream>>>(nidx, eidx, part, csr);      // 1536 blocks, XCD-pinned

  // x -> bf16 (6.4M packed words) — must run after k_fill3 (part aliases xbf)
  k_tobf<<<25000, 256, 0, stream>>>((const float2*)x, xbf);

  const int BLK_A = (N_EDGES * 64 + 255) / 256;   // 5000
  const int BLK_B = (N_NODES * 64 + 255) / 256;   // 25000
  const int BLK_G = (N_EDGES + 63) / 64;          // 313
  const int BLK_GN = (N_NODES + 63) / 64;         // 1563

  // layer 1: x -> h (relu)
  k_passAbf<<<BLK_A, 256, 0, stream>>>(xbf, csr, off, cnt, ebuf);
  k_gemm128b<<<BLK_G, 256, 0, stream>>>(ebuf, W1, eb2bf);
  k_passBbf<true><<<BLK_B, 256, 0, stream>>>(eb2bf, csr, off, cnt, b1, hbf);

  // layer 2: h -> h (relu)
  k_passAbf<<<BLK_A, 256, 0, stream>>>(hbf, csr, off, cnt, ebuf);
  k_gemm128b<<<BLK_G, 256, 0, stream>>>(ebuf, W2, eb2bf);
  k_passBbf<true><<<BLK_B, 256, 0, stream>>>(eb2bf, csr, off, cnt, b2, hbf);

  // layer 3: node-GEMM first, then 64-wide gathers
  k_gemm_node_b<<<BLK_GN, 128, 0, stream>>>(hbf, W3, hw3);
  k_passA64b<<<BLK_A, 256, 0, stream>>>((const unsigned short*)hw3, csr, off, cnt, eb3);
  k_passB64b<<<BLK_B, 256, 0, stream>>>(eb3, csr, off, cnt, b3, out);
}

// Round 13
// 608.083 us; speedup vs baseline: 1.0905x; 1.0198x over previous
//
#include <hip/hip_runtime.h>

#define N_NODES 100000
#define N_EDGES 20000
#define NNZV    1600000
#define NSEG    (N_EDGES + N_NODES)
#define FIN     128
#define HSLICES 64
#define SLICE   (NNZV / HSLICES)    // 25000
#define NR_E    4                   // hist: edge ranges of 5000
#define NR_N    16                  // hist: node ranges of 6250
#define NRANGES (NR_E + NR_N)       // 20 (hist decomposition)

// ---- bf16 helpers (RTNE pack, cheap unpack) ----
__device__ __forceinline__ unsigned short f2bf(float f) {
  unsigned u = __float_as_uint(f);
  unsigned r = u + 0x7fffu + ((u >> 16) & 1u);
  return (unsigned short)(r >> 16);
}
__device__ __forceinline__ unsigned pack2(float lo, float hi) {
  return (unsigned)f2bf(lo) | ((unsigned)f2bf(hi) << 16);
}
__device__ __forceinline__ float bf_lo(unsigned w) { return __uint_as_float(w << 16); }
__device__ __forceinline__ float bf_hi(unsigned w) { return __uint_as_float(w & 0xffff0000u); }

// hist range decomposition (20 ranges)
__device__ __forceinline__ void range_info(int r, const int* nidx, const int* eidx,
                                           const int*& keys, int& base, int& size, int& gbin_off) {
  if (r < NR_E) { keys = eidx; base = r * 5000; size = 5000; gbin_off = 0; }
  else { keys = nidx; base = (r - NR_E) * 6250; size = 6250; gbin_off = N_EDGES; }
}

// ---------------- histogram count: part[s][bin], LDS, no device atomics ----------------

__global__ __launch_bounds__(256) void k_hist(const int* __restrict__ nidx,
                                              const int* __restrict__ eidx,
                                              int* __restrict__ part) {
  __shared__ int hist[6250];
  int r = blockIdx.x % NRANGES, s = blockIdx.x / NRANGES;
  const int* keys; int base, size, gbin_off;
  range_info(r, nidx, eidx, keys, base, size, gbin_off);
  for (int i = threadIdx.x; i < size; i += 256) hist[i] = 0;
  __syncthreads();
  int lo = s * SLICE, hi = lo + SLICE;
  for (int i = lo + threadIdx.x; i < hi; i += 256) {
    int k = keys[i];
    unsigned d = (unsigned)(k - base);
    if (d < (unsigned)size) atomicAdd(&hist[d], 1);
  }
  __syncthreads();
  int* dst = part + (size_t)s * NSEG + gbin_off + base;
  for (int i = threadIdx.x; i < size; i += 256) dst[i] = hist[i];
}

__global__ void k_hreduce(const int* __restrict__ part, int* __restrict__ cnt) {
  int b = blockIdx.x * 256 + threadIdx.x;
  if (b >= NSEG) return;
  int sum = 0;
  for (int s = 0; s < HSLICES; ++s) sum += part[(size_t)s * NSEG + b];
  cnt[b] = sum;
}

// ---------------- scans ----------------

__global__ void k_scan1(const int* __restrict__ cnt, int* __restrict__ incl,
                        int* __restrict__ bsum) {
  __shared__ int s[1024];
  int gid = blockIdx.x * 1024 + threadIdx.x;
  int v = (gid < NSEG) ? cnt[gid] : 0;
  s[threadIdx.x] = v;
  __syncthreads();
  for (int d = 1; d < 1024; d <<= 1) {
    int t = (threadIdx.x >= d) ? s[threadIdx.x - d] : 0;
    __syncthreads();
    s[threadIdx.x] += t;
    __syncthreads();
  }
  if (gid < NSEG) incl[gid] = s[threadIdx.x];
  if (threadIdx.x == 1023) bsum[blockIdx.x] = s[1023];
}

__global__ void k_scan2(int* __restrict__ bsum, int nb) {
  __shared__ int s[128];
  int v = (threadIdx.x < nb) ? bsum[threadIdx.x] : 0;
  s[threadIdx.x] = v;
  __syncthreads();
  for (int d = 1; d < 128; d <<= 1) {
    int t = (threadIdx.x >= (unsigned)d) ? s[threadIdx.x - d] : 0;
    __syncthreads();
    s[threadIdx.x] += t;
    __syncthreads();
  }
  if (threadIdx.x < nb) bsum[threadIdx.x] = s[threadIdx.x] - v;  // exclusive
}

__global__ void k_scan3(int* __restrict__ off, const int* __restrict__ cnt,
                        const int* __restrict__ bsum) {
  int gid = blockIdx.x * 1024 + threadIdx.x;
  if (gid < NSEG) off[gid] = off[gid] - cnt[gid] + bsum[blockIdx.x];
}

// ---------------- sbase: part[s][b] (in-place) -> off[b] + sum_{s'<s} part[s'][b] ----------------

__global__ void k_sbase(int* __restrict__ part, const int* __restrict__ off) {
  int b = blockIdx.x * 256 + threadIdx.x;
  if (b >= NSEG) return;
  int running = off[b];
  for (int s = 0; s < HSLICES; ++s) {
    size_t idx = (size_t)s * NSEG + b;
    int t = part[idx];
    part[idx] = running;
    running += t;
  }
}

// ---------------- fill: LDS-ranked, zero device atomics, XCD-pinned ranges ----------------
// (round-12 version: isolated counter delta positive — 83.2us vs 85.6us, FETCH -9MB)

__global__ __launch_bounds__(256) void k_fill3(const int* __restrict__ nidx,
                                               const int* __restrict__ eidx,
                                               const int* __restrict__ sbase,
                                               int* __restrict__ csr) {
  __shared__ int rank[6250];
  int g = blockIdx.x;
  int xcd = g & 7;
  int i2 = g >> 3;            // 0..191
  int li = i2 % 3;            // local range index
  int s  = i2 / 3;            // slice 0..63
  int r  = li * 8 + xcd;      // 0..23
  const int *keys, *vals; int base, size, gbin_off;
  if (r < 8) { keys = eidx; vals = nidx; base = r * 2500; size = 2500; gbin_off = 0; }
  else { keys = nidx; vals = eidx; base = (r - 8) * 6250; size = 6250; gbin_off = N_EDGES; }
  for (int i = threadIdx.x; i < size; i += 256) rank[i] = 0;
  __syncthreads();
  int lo = s * SLICE, hi = lo + SLICE;
  const int* sb = sbase + (size_t)s * NSEG + gbin_off;
  for (int i = lo + threadIdx.x; i < hi; i += 256) {
    int k = keys[i];
    unsigned d = (unsigned)(k - base);
    if (d < (unsigned)size) {
      int v = vals[i];
      int rk = atomicAdd(&rank[d], 1);
      csr[sb[k] + rk] = v;
    }
  }
}

// ---------------- x (f32) -> packed bf16 ----------------

__global__ void k_tobf(const float2* __restrict__ x2, unsigned* __restrict__ xbf) {
  int t = blockIdx.x * 256 + threadIdx.x;   // grid sized exactly
  float2 v = x2[t];
  xbf[t] = pack2(v.x, v.y);
}

// ---------------- gather node->edge, 128-wide bf16 table, one wave/edge, 8-deep ----------------
// (round-10 version: f32 output)

__global__ __launch_bounds__(256) void k_passAbf(const unsigned* __restrict__ tab,
                                                 const int* __restrict__ csr,
                                                 const int* __restrict__ off,
                                                 const int* __restrict__ cnt,
                                                 float* __restrict__ ebuf) {
  int wave = (blockIdx.x * blockDim.x + threadIdx.x) >> 6;
  int lane = threadIdx.x & 63;
  if (wave >= N_EDGES) return;
  int beg = off[wave];
  int m   = cnt[wave];
  const unsigned* src = tab + lane;
  float accx = 0.f, accy = 0.f;
  int idxv = 0;
  int j = 0;
  for (; j + 8 <= m; j += 8) {
    int jm = j & 63;
    if (jm == 0) {
      int p = j + lane;
      idxv = (p < m) ? __builtin_nontemporal_load(csr + beg + p) : 0;
    }
    int n0 = __shfl(idxv, jm);
    int n1 = __shfl(idxv, jm + 1);
    int n2 = __shfl(idxv, jm + 2);
    int n3 = __shfl(idxv, jm + 3);
    int n4 = __shfl(idxv, jm + 4);
    int n5 = __shfl(idxv, jm + 5);
    int n6 = __shfl(idxv, jm + 6);
    int n7 = __shfl(idxv, jm + 7);
    unsigned w0 = src[(size_t)n0 * 64];
    unsigned w1 = src[(size_t)n1 * 64];
    unsigned w2 = src[(size_t)n2 * 64];
    unsigned w3 = src[(size_t)n3 * 64];
    unsigned w4 = src[(size_t)n4 * 64];
    unsigned w5 = src[(size_t)n5 * 64];
    unsigned w6 = src[(size_t)n6 * 64];
    unsigned w7 = src[(size_t)n7 * 64];
    accx += ((bf_lo(w0) + bf_lo(w1)) + (bf_lo(w2) + bf_lo(w3))) +
            ((bf_lo(w4) + bf_lo(w5)) + (bf_lo(w6) + bf_lo(w7)));
    accy += ((bf_hi(w0) + bf_hi(w1)) + (bf_hi(w2) + bf_hi(w3))) +
            ((bf_hi(w4) + bf_hi(w5)) + (bf_hi(w6) + bf_hi(w7)));
  }
  for (; j < m; ++j) {
    int jm = j & 63;
    if (jm == 0) {
      int p = j + lane;
      idxv = (p < m) ? __builtin_nontemporal_load(csr + beg + p) : 0;
    }
    int n0 = __shfl(idxv, jm);
    unsigned w = src[(size_t)n0 * 64];
    accx += bf_lo(w); accy += bf_hi(w);
  }
  float binv = (m > 0) ? (1.f / (float)m) : 0.f;
  *reinterpret_cast<float2*>(ebuf + (size_t)wave * FIN + lane * 2) =
      make_float2(accx * binv, accy * binv);
}

// ---------------- edge GEMM: f32 A [20000][128] @ f32 W [128][128] -> packed bf16 Out ----------------
// (round-10 version)

__global__ void k_gemm128b(const float* __restrict__ A, const float* __restrict__ W,
                           unsigned* __restrict__ Out) {
  __shared__ float As[64][33];
  __shared__ float Ws[32][128];
  int tid = threadIdx.x;
  int tx = tid % 16, ty = tid / 16;
  int row0 = blockIdx.x * 64;
  float acc[4][8];
#pragma unroll
  for (int i = 0; i < 4; ++i)
#pragma unroll
    for (int j = 0; j < 8; ++j) acc[i][j] = 0.f;

  for (int kc = 0; kc < FIN; kc += 32) {
    for (int i = tid; i < 64 * 32; i += 256) {
      int r = i >> 5, k = i & 31;
      int gr = row0 + r;
      As[r][k] = (gr < N_EDGES) ? A[(size_t)gr * FIN + kc + k] : 0.f;
    }
    for (int i = tid; i < 32 * 128; i += 256) {
      int k = i >> 7, cc = i & 127;
      Ws[k][cc] = W[(size_t)(kc + k) * 128 + cc];
    }
    __syncthreads();
#pragma unroll
    for (int k = 0; k < 32; ++k) {
      float a[4];
#pragma unroll
      for (int i = 0; i < 4; ++i) a[i] = As[ty * 4 + i][k];
      float w[8];
#pragma unroll
      for (int j = 0; j < 8; ++j) w[j] = Ws[k][tx * 8 + j];
#pragma unroll
      for (int i = 0; i < 4; ++i)
#pragma unroll
        for (int j = 0; j < 8; ++j) acc[i][j] += a[i] * w[j];
    }
    __syncthreads();
  }
#pragma unroll
  for (int i = 0; i < 4; ++i) {
    int gr = row0 + ty * 4 + i;
    if (gr < N_EDGES) {
#pragma unroll
      for (int jj = 0; jj < 4; ++jj)
        Out[(size_t)gr * 64 + tx * 4 + jj] = pack2(acc[i][2 * jj], acc[i][2 * jj + 1]);
    }
  }
}

// ---------------- gather edge->node, 128-wide bf16 table, +bias/relu, out packed bf16 h ----------------

template <bool RELU>
__global__ __launch_bounds__(256) void k_passBbf(const unsigned* __restrict__ tab,
                                                 const int* __restrict__ csr,
                                                 const int* __restrict__ off,
                                                 const int* __restrict__ cnt,
                                                 const float* __restrict__ bias,
                                                 unsigned* __restrict__ hbf) {
  int wave = (blockIdx.x * blockDim.x + threadIdx.x) >> 6;
  int lane = threadIdx.x & 63;
  if (wave >= N_NODES) return;
  int beg = off[N_EDGES + wave];
  int m   = cnt[N_EDGES + wave];
  const unsigned* src = tab + lane;
  float accx = 0.f, accy = 0.f;
  int idxv = 0;
  int j = 0;
  for (; j + 8 <= m; j += 8) {
    int jm = j & 63;
    if (jm == 0) {
      int p = j + lane;
      idxv = (p < m) ? __builtin_nontemporal_load(csr + beg + p) : 0;
    }
    int n0 = __shfl(idxv, jm);
    int n1 = __shfl(idxv, jm + 1);
    int n2 = __shfl(idxv, jm + 2);
    int n3 = __shfl(idxv, jm + 3);
    int n4 = __shfl(idxv, jm + 4);
    int n5 = __shfl(idxv, jm + 5);
    int n6 = __shfl(idxv, jm + 6);
    int n7 = __shfl(idxv, jm + 7);
    unsigned w0 = src[(size_t)n0 * 64];
    unsigned w1 = src[(size_t)n1 * 64];
    unsigned w2 = src[(size_t)n2 * 64];
    unsigned w3 = src[(size_t)n3 * 64];
    unsigned w4 = src[(size_t)n4 * 64];
    unsigned w5 = src[(size_t)n5 * 64];
    unsigned w6 = src[(size_t)n6 * 64];
    unsigned w7 = src[(size_t)n7 * 64];
    accx += ((bf_lo(w0) + bf_lo(w1)) + (bf_lo(w2) + bf_lo(w3))) +
            ((bf_lo(w4) + bf_lo(w5)) + (bf_lo(w6) + bf_lo(w7)));
    accy += ((bf_hi(w0) + bf_hi(w1)) + (bf_hi(w2) + bf_hi(w3))) +
            ((bf_hi(w4) + bf_hi(w5)) + (bf_hi(w6) + bf_hi(w7)));
  }
  for (; j < m; ++j) {
    int jm = j & 63;
    if (jm == 0) {
      int p = j + lane;
      idxv = (p < m) ? __builtin_nontemporal_load(csr + beg + p) : 0;
    }
    int n0 = __shfl(idxv, jm);
    unsigned w = src[(size_t)n0 * 64];
    accx += bf_lo(w); accy += bf_hi(w);
  }
  float dinv = (m > 0) ? (1.f / (float)m) : 0.f;
  float ox = accx * dinv + bias[lane * 2];
  float oy = accy * dinv + bias[lane * 2 + 1];
  if (RELU) { ox = fmaxf(ox, 0.f); oy = fmaxf(oy, 0.f); }
  hbf[(size_t)wave * 64 + lane] = pack2(ox, oy);
}

// ---------------- node GEMM (layer 3): bf16 h [100000][128] @ f32 W3 [128][64] -> packed bf16 ----------------
// (round-10 known-good version, 128 threads)

__global__ void k_gemm_node_b(const unsigned* __restrict__ hbf, const float* __restrict__ W,
                              unsigned* __restrict__ Out) {
  __shared__ float As[64][33];
  __shared__ float Ws[32][64];
  int tid = threadIdx.x;            // 128 threads
  int tx = tid % 8, ty = tid / 8;
  int row0 = blockIdx.x * 64;
  float acc[4][8];
#pragma unroll
  for (int i = 0; i < 4; ++i)
#pragma unroll
    for (int j = 0; j < 8; ++j) acc[i][j] = 0.f;

  for (int kc = 0; kc < FIN; kc += 32) {
    for (int i = tid; i < 64 * 16; i += 128) {
      int r = i >> 4, kp = i & 15;
      int gr = row0 + r;
      unsigned w = (gr < N_NODES) ? hbf[(size_t)gr * 64 + (kc >> 1) + kp] : 0u;
      As[r][2 * kp]     = bf_lo(w);
      As[r][2 * kp + 1] = bf_hi(w);
    }
    for (int i = tid; i < 32 * 64; i += 128) {
      int k = i >> 6, cc = i & 63;
      Ws[k][cc] = W[(size_t)(kc + k) * 64 + cc];
    }
    __syncthreads();
#pragma unroll
    for (int k = 0; k < 32; ++k) {
      float a[4];
#pragma unroll
      for (int i = 0; i < 4; ++i) a[i] = As[ty * 4 + i][k];
      float w[8];
#pragma unroll
      for (int j = 0; j < 8; ++j) w[j] = Ws[k][tx * 8 + j];
#pragma unroll
      for (int i = 0; i < 4; ++i)
#pragma unroll
        for (int j = 0; j < 8; ++j) acc[i][j] += a[i] * w[j];
    }
    __syncthreads();
  }
#pragma unroll
  for (int i = 0; i < 4; ++i) {
    int gr = row0 + ty * 4 + i;
    if (gr < N_NODES) {
#pragma unroll
      for (int jj = 0; jj < 4; ++jj)
        Out[(size_t)gr * 32 + tx * 4 + jj] = pack2(acc[i][2 * jj], acc[i][2 * jj + 1]);
    }
  }
}

// ---------------- gather node->edge, 64-wide bf16 (ushort/lane), out bf16 ----------------

__global__ __launch_bounds__(256) void k_passA64b(const unsigned short* __restrict__ tab,
                                                  const int* __restrict__ csr,
                                                  const int* __restrict__ off,
                                                  const int* __restrict__ cnt,
                                                  unsigned short* __restrict__ eb3) {
  int wave = (blockIdx.x * blockDim.x + threadIdx.x) >> 6;
  int lane = threadIdx.x & 63;
  if (wave >= N_EDGES) return;
  int beg = off[wave];
  int m   = cnt[wave];
  const unsigned short* src = tab + lane;
  float acc = 0.f;
  int idxv = 0;
  int j = 0;
  for (; j + 8 <= m; j += 8) {
    int jm = j & 63;
    if (jm == 0) {
      int p = j + lane;
      idxv = (p < m) ? __builtin_nontemporal_load(csr + beg + p) : 0;
    }
    int n0 = __shfl(idxv, jm);
    int n1 = __shfl(idxv, jm + 1);
    int n2 = __shfl(idxv, jm + 2);
    int n3 = __shfl(idxv, jm + 3);
    int n4 = __shfl(idxv, jm + 4);
    int n5 = __shfl(idxv, jm + 5);
    int n6 = __shfl(idxv, jm + 6);
    int n7 = __shfl(idxv, jm + 7);
    float v0 = __uint_as_float((unsigned)src[(size_t)n0 * 64] << 16);
    float v1 = __uint_as_float((unsigned)src[(size_t)n1 * 64] << 16);
    float v2 = __uint_as_float((unsigned)src[(size_t)n2 * 64] << 16);
    float v3 = __uint_as_float((unsigned)src[(size_t)n3 * 64] << 16);
    float v4 = __uint_as_float((unsigned)src[(size_t)n4 * 64] << 16);
    float v5 = __uint_as_float((unsigned)src[(size_t)n5 * 64] << 16);
    float v6 = __uint_as_float((unsigned)src[(size_t)n6 * 64] << 16);
    float v7 = __uint_as_float((unsigned)src[(size_t)n7 * 64] << 16);
    acc += ((v0 + v1) + (v2 + v3)) + ((v4 + v5) + (v6 + v7));
  }
  for (; j < m; ++j) {
    int jm = j & 63;
    if (jm == 0) {
      int p = j + lane;
      idxv = (p < m) ? __builtin_nontemporal_load(csr + beg + p) : 0;
    }
    int n0 = __shfl(idxv, jm);
    acc += __uint_as_float((unsigned)src[(size_t)n0 * 64] << 16);
  }
  float binv = (m > 0) ? (1.f / (float)m) : 0.f;
  eb3[(size_t)wave * 64 + lane] = f2bf(acc * binv);
}

// ---------------- gather edge->node, 64-wide bf16 table (2.56 MB), out f32 ----------------

__global__ __launch_bounds__(256) void k_passB64b(const unsigned short* __restrict__ tab,
                                                  const int* __restrict__ csr,
                                                  const int* __restrict__ off,
                                                  const int* __restrict__ cnt,
                                                  const float* __restrict__ bias,
                                                  float* __restrict__ out) {
  int wave = (blockIdx.x * blockDim.x + threadIdx.x) >> 6;
  int lane = threadIdx.x & 63;
  if (wave >= N_NODES) return;
  int beg = off[N_EDGES + wave];
  int m   = cnt[N_EDGES + wave];
  const unsigned short* src = tab + lane;
  float acc = 0.f;
  int idxv = 0;
  int j = 0;
  for (; j + 8 <= m; j += 8) {
    int jm = j & 63;
    if (jm == 0) {
      int p = j + lane;
      idxv = (p < m) ? __builtin_nontemporal_load(csr + beg + p) : 0;
    }
    int n0 = __shfl(idxv, jm);
    int n1 = __shfl(idxv, jm + 1);
    int n2 = __shfl(idxv, jm + 2);
    int n3 = __shfl(idxv, jm + 3);
    int n4 = __shfl(idxv, jm + 4);
    int n5 = __shfl(idxv, jm + 5);
    int n6 = __shfl(idxv, jm + 6);
    int n7 = __shfl(idxv, jm + 7);
    float v0 = __uint_as_float((unsigned)src[(size_t)n0 * 64] << 16);
    float v1 = __uint_as_float((unsigned)src[(size_t)n1 * 64] << 16);
    float v2 = __uint_as_float((unsigned)src[(size_t)n2 * 64] << 16);
    float v3 = __uint_as_float((unsigned)src[(size_t)n3 * 64] << 16);
    float v4 = __uint_as_float((unsigned)src[(size_t)n4 * 64] << 16);
    float v5 = __uint_as_float((unsigned)src[(size_t)n5 * 64] << 16);
    float v6 = __uint_as_float((unsigned)src[(size_t)n6 * 64] << 16);
    float v7 = __uint_as_float((unsigned)src[(size_t)n7 * 64] << 16);
    acc += ((v0 + v1) + (v2 + v3)) + ((v4 + v5) + (v6 + v7));
  }
  for (; j < m; ++j) {
    int jm = j & 63;
    if (jm == 0) {
      int p = j + lane;
      idxv = (p < m) ? __builtin_nontemporal_load(csr + beg + p) : 0;
    }
    int n0 = __shfl(idxv, jm);
    acc += __uint_as_float((unsigned)src[(size_t)n0 * 64] << 16);
  }
  float dinv = (m > 0) ? (1.f / (float)m) : 0.f;
  out[(size_t)wave * 64 + lane] = acc * dinv + bias[lane];
}

// ---------------- launch ----------------

extern "C" void kernel_launch(void* const* d_in, const int* in_sizes, int n_in,
                              void* d_out, int out_size, void* d_ws, size_t ws_size,
                              hipStream_t stream) {
  const float* x  = (const float*)d_in[0];
  const float* W1 = (const float*)d_in[1];
  const float* b1 = (const float*)d_in[2];
  const float* W2 = (const float*)d_in[3];
  const float* b2 = (const float*)d_in[4];
  const float* W3 = (const float*)d_in[5];
  const float* b3 = (const float*)d_in[6];
  const int* nidx = (const int*)d_in[7];
  const int* eidx = (const int*)d_in[8];

  // workspace layout (bytes) — round-10 layout
  const size_t OFF_CNT  = 0;          // int[120000]
  const size_t OFF_OFF  = 480000;     // int[120000]
  const size_t OFF_BSUM = 1440000;    // int[128]
  const size_t OFF_CSR  = 1441792;    // int[3200000]            (12.8 MB)
  const size_t OFF_EB   = 14241792;   // f32[20000*128] 10.24 MB ; layer-3 eb3 aliases
  const size_t OFF_EB2  = 24481792;   // u32[20000*64]  5.12 MB  (bf16 edge feats)
  const size_t OFF_XBF  = 29601792;   // u32[100000*64] 25.6 MB  (bf16 x) ; part[64][NSEG]=30.72MB aliases
  const size_t OFF_HBF  = 55201792;   //   XBF..XBF+30.72MB (dead before k_tobf / layer-1 passBbf)
  const size_t NEEDED   = 80801792;
  if (ws_size < NEEDED) return;

  char* ws = (char*)d_ws;
  int*      cnt   = (int*)(ws + OFF_CNT);
  int*      off   = (int*)(ws + OFF_OFF);
  int*      bsum  = (int*)(ws + OFF_BSUM);
  int*      csr   = (int*)(ws + OFF_CSR);
  int*      part  = (int*)(ws + OFF_XBF);    // 64*120000*4 = 30.72 MB, dead after k_fill3
  float*    ebuf  = (float*)(ws + OFF_EB);   // f32 edge agg (layers 1-2)
  unsigned* eb2bf = (unsigned*)(ws + OFF_EB2);
  unsigned* xbf   = (unsigned*)(ws + OFF_XBF);
  unsigned* hw3   = (unsigned*)(ws + OFF_XBF);          // layer 3: h@W3, packed bf16 [100000][32 u32]
  unsigned short* eb3 = (unsigned short*)(ws + OFF_EB); // layer 3: edge agg bf16 [20000][64]
  unsigned* hbf   = (unsigned*)(ws + OFF_HBF);
  float*    out   = (float*)d_out;

  hipMemsetAsync(ws + OFF_BSUM, 0, 512, stream);  // bsum

  // CSR build — zero device-scope atomics
  k_hist<<<NRANGES * HSLICES, 256, 0, stream>>>(nidx, eidx, part);       // 1280 blocks
  k_hreduce<<<(NSEG + 255) / 256, 256, 0, stream>>>(part, cnt);
  const int nb = (NSEG + 1023) / 1024;  // 118
  k_scan1<<<nb, 1024, 0, stream>>>(cnt, off, bsum);
  k_scan2<<<1, 128, 0, stream>>>(bsum, nb);
  k_scan3<<<nb, 1024, 0, stream>>>(off, cnt, bsum);
  k_sbase<<<(NSEG + 255) / 256, 256, 0, stream>>>(part, off);
  k_fill3<<<24 * HSLICES, 256, 0, stream>>>(nidx, eidx, part, csr);      // 1536 blocks, XCD-pinned

  // x -> bf16 (6.4M packed words) — must run after k_fill3 (part aliases xbf)
  k_tobf<<<25000, 256, 0, stream>>>((const float2*)x, xbf);

  const int BLK_A = (N_EDGES * 64 + 255) / 256;   // 5000
  const int BLK_B = (N_NODES * 64 + 255) / 256;   // 25000
  const int BLK_G = (N_EDGES + 63) / 64;          // 313
  const int BLK_GN = (N_NODES + 63) / 64;         // 1563

  // layer 1: x -> h (relu)
  k_passAbf<<<BLK_A, 256, 0, stream>>>(xbf, csr, off, cnt, ebuf);
  k_gemm128b<<<BLK_G, 256, 0, stream>>>(ebuf, W1, eb2bf);
  k_passBbf<true><<<BLK_B, 256, 0, stream>>>(eb2bf, csr, off, cnt, b1, hbf);

  // layer 2: h -> h (relu)
  k_passAbf<<<BLK_A, 256, 0, stream>>>(hbf, csr, off, cnt, ebuf);
  k_gemm128b<<<BLK_G, 256, 0, stream>>>(ebuf, W2, eb2bf);
  k_passBbf<true><<<BLK_B, 256, 0, stream>>>(eb2bf, csr, off, cnt, b2, hbf);

  // layer 3: node-GEMM first, then 64-wide gathers
  k_gemm_node_b<<<BLK_GN, 128, 0, stream>>>(hbf, W3, hw3);
  k_passA64b<<<BLK_A, 256, 0, stream>>>((const unsigned short*)hw3, csr, off, cnt, eb3);
  k_passB64b<<<BLK_B, 256, 0, stream>>>(eb3, csr, off, cnt, b3, out);
}